// Round 18
// baseline (514.779 us; speedup 1.0000x reference)
//
#include <hip/hip_runtime.h>

// SlayerLoihiMLP: bit-exact f32 replication of the numpy reference (verified
// r5-r17, absmax 0.0). Round 18 = r15/r17 (best known, 381 us) with the two
// prelude kernels fused: k0_list reads X once and emits per-(b,t) ascending
// index lists directly (identical XL/XC bytes; mask intermediate deleted).
// k1/k2 byte-identical to r17.
// Exactness invariants:
//  - GEMM: per-output ordered ascending-i f32 sum; skipping x==0 terms is
//    bit-exact (RNE running sums never produce -0.0; +0.0 adds are identity).
//  - conv: f32 mul then add (contract OFF file-wide), taps tau-descending
//    87..0 per output col; out-of-range taps fetched as exact 0.0f (their
//    mul/add terms are IEEE identities); taps = (64*SRM)/64 exact; *64; trunc.
//  - neuron dynamics: bit-exact int32 with jnp wrap semantics (decay_i).
//  - float2 packing pairs INDEPENDENT channel accumulators.

#pragma clang fp contract(off)

constexpr int kT     = 512;
constexpr int kCIN   = 512;
constexpr int kHID   = 1024;
constexpr int kCOUT  = 256;
constexpr int kB     = 32;
constexpr int kTHETA = 5120;   // 80 << 6
constexpr int kOT1   = 16;     // k1 channels per block
constexpr int kOT2   = 8;      // k2 channels per block
constexpr int kHP1   = 20;     // k1 h row pitch (floats): 80B, 8-lane period
                               // covers all 32 banks -> conflict-free b128
constexpr int kHP2   = 12;     // k2 h row pitch (r13-proven)
constexpr int kSBP   = 516;    // sbuf row pitch (bytes)
constexpr int kCURP1 = 524;    // k1 cur pitch (ints): int4-aligned stores
constexpr int kCURP2 = 522;    // k2 cur pitch (r13-proven)
constexpr int kLCAP  = 128;    // list capacity per (b,t); mean nnz=25.6

// ---- SRM kernel taps at compile time: v[tau] = (64*SRM_KERNEL[tau])/64 ----
struct Ker { float v[96]; int n; };
constexpr Ker mk_ker() {
    Ker K{}; int u = 64, v = 64; K.v[0] = 1.0f; int i = 1;
    while (v > 0 && i < 96) {
        u = (u * 3072) >> 12;
        v = ((v * 3968) >> 12) + u;
        K.v[i++] = (float)v / 64.0f;   // exact (v <= 194)
    }
    K.n = i; return K;
}
constexpr Ker KER = mk_ker();
static_assert(KER.n == 88, "SRM kernel length must be 88");
static_assert(KER.v[87] == 0.0f, "tap 87 must be the exact zero tail tap");
__device__ __constant__ Ker KERC = mk_ker();

__device__ __forceinline__ float2 pkmul(const float2 a, const float b) {
    return make_float2(a.x * b, a.y * b);
}
__device__ __forceinline__ float2 pkadd(const float2 a, const float2 b) {
    return make_float2(a.x + b.x, a.y + b.y);
}

// wrap-exact mirror of jnp: s = sign(x); s * ((s*x*mult) >> 12), int32 wrap
__device__ __forceinline__ int decay_i(int x, int mult) {
    unsigned ax = (x >= 0) ? (unsigned)x : (0u - (unsigned)x);
    unsigned p  = ax * (unsigned)mult;
    int sh = ((int)p) >> 12;
    return (x >= 0) ? sh : (int)(0u - (unsigned)sh);
}

// ==== k0_list: X -> per-(b,t) ascending index lists XL[bt][k], XC[bt] ========
// One pass over X (coalesced over t-lanes); identical output bytes to the
// former k0_pack + k0b_list pair (same ascending-i order, same !=0 test).
__global__ __launch_bounds__(256) void k0_list(const float* __restrict__ X,
                                               unsigned short* __restrict__ XL,
                                               unsigned short* __restrict__ XC) {
    const int bt = blockIdx.x * 256 + threadIdx.x;    // b*512 + t, 16384 total
    const int b = bt >> 9, t = bt & 511;
    const float* xp = X + ((size_t)b * kCIN) * kT + t;
    unsigned short* row = XL + (size_t)bt * kLCAP;
    int cnt = 0;
    for (int i = 0; i < kCIN; ++i) {
        if (xp[(size_t)i * kT] != 0.0f) {             // coalesced over t-lanes
            if (cnt < kLCAP) row[cnt] = (unsigned short)i;
            ++cnt;
        }
    }
    XC[bt] = (unsigned short)min(cnt, kLCAP);
}

// ===== k1: list-gather GEMM + 4col/4ch conv + int32 scan; 16 ch/block ========
#define GADD16(II) { const int ii_ = (II); \
    const float4 f0 = *reinterpret_cast<const float4*>(&w0[ii_ * 4]); \
    const float4 f1 = *reinterpret_cast<const float4*>(&w1[ii_ * 4]); \
    const float4 f2 = *reinterpret_cast<const float4*>(&w2[ii_ * 4]); \
    const float4 f3 = *reinterpret_cast<const float4*>(&w3[ii_ * 4]); \
    A0 = pkadd(A0, make_float2(f0.x, f0.y)); A1 = pkadd(A1, make_float2(f0.z, f0.w)); \
    A2 = pkadd(A2, make_float2(f1.x, f1.y)); A3 = pkadd(A3, make_float2(f1.z, f1.w)); \
    A4 = pkadd(A4, make_float2(f2.x, f2.y)); A5 = pkadd(A5, make_float2(f2.z, f2.w)); \
    A6 = pkadd(A6, make_float2(f3.x, f3.y)); A7 = pkadd(A7, make_float2(f3.z, f3.w)); }

// accumulate one h row (4 ch as float4 R) into col-d accs with tap KV
#define ACCROW(CA, CB, R, KV) \
    CA = pkadd(CA, pkmul(make_float2((R).x, (R).y), (KV))); \
    CB = pkadd(CB, pkmul(make_float2((R).z, (R).w), (KV)));

__global__ __launch_bounds__(512, 6) void k1_fused(const unsigned short* __restrict__ XL,
                                                   const unsigned short* __restrict__ XC,
                                                   const float* __restrict__ W,
                                                   unsigned short* __restrict__ SPW) {
    // aliased region: W (32K) -> h row-mod-4 arrays 4 x [128][20] (40960B)
    //                 -> cur [16][524] (33536B)
    __shared__ __align__(16) unsigned char regn[40960];
    __shared__ unsigned char sbuf[kOT1 * kSBP];   // 8256 B

    float* w0 = reinterpret_cast<float*>(regn);            // [512][4] ch0-3
    float* w1 = reinterpret_cast<float*>(regn + 8192);     // ch4-7
    float* w2 = reinterpret_cast<float*>(regn + 16384);    // ch8-11
    float* w3 = reinterpret_cast<float*>(regn + 24576);    // ch12-15
    int*   cur = reinterpret_cast<int*>(regn);             // [16][524]

    const int t     = threadIdx.x;
    const int b     = blockIdx.x >> 6;            // 64 blocks per batch
    const int oblk  = blockIdx.x & 63;
    const int obase = oblk * kOT1;

    for (int idx = t; idx < kOT1 * kCIN; idx += 512) {
        const int j = idx >> 9, i = idx & 511;    // j = channel 0..15
        float* wq = reinterpret_cast<float*>(regn + (j >> 2) * 8192);
        wq[i * 4 + (j & 3)] = W[(size_t)(obase + j) * kCIN + i];
    }
    __syncthreads();

    // ---- list gather: ordered ascending-i adds of W columns where x==1 ----
    const int bt = (b << 9) | t;
    const int cnt = XC[bt];
    const uint4* lrow = reinterpret_cast<const uint4*>(XL + (size_t)bt * kLCAP);
    float2 A0 = make_float2(0.f, 0.f), A1 = A0, A2 = A0, A3 = A0,
           A4 = A0, A5 = A0, A6 = A0, A7 = A0;
    for (int k8 = 0; k8 * 8 < cnt; ++k8) {
        const uint4 le = lrow[k8];
        const int base = k8 * 8;
#define GE1(E, V) if (base + (E) < cnt) GADD16((int)(V))
        GE1(0, le.x & 0xffffu) GE1(1, le.x >> 16)
        GE1(2, le.y & 0xffffu) GE1(3, le.y >> 16)
        GE1(4, le.z & 0xffffu) GE1(5, le.z >> 16)
        GE1(6, le.w & 0xffffu) GE1(7, le.w >> 16)
#undef GE1
    }
    __syncthreads();   // all W reads complete (h overwrites W region)

    // ---- stage h row t into array (t&3), row (t>>2): 16 ch + 4 pad ----
    {
        float* hr = reinterpret_cast<float*>(regn + (t & 3) * 10240)
                    + (size_t)(t >> 2) * kHP1;
        *reinterpret_cast<float4*>(hr + 0)  = make_float4(A0.x, A0.y, A1.x, A1.y);
        *reinterpret_cast<float4*>(hr + 4)  = make_float4(A2.x, A2.y, A3.x, A3.y);
        *reinterpret_cast<float4*>(hr + 8)  = make_float4(A4.x, A4.y, A5.x, A5.y);
        *reinterpret_cast<float4*>(hr + 12) = make_float4(A6.x, A6.y, A7.x, A7.y);
    }
    __syncthreads();

    // ---- conv: thread (q = t&127, qt = t>>7) -> cols 4q..4q+3, ch 4qt..+3 ----
    // iterate s = q-m descending 22..0 (rows ascending); per col d the tap
    // sequence is tau = 4s+d-j, strictly descending 87..0 across the loop;
    // out-of-range taus fetch exact 0.0f (identity terms).
    const int q = t & 127, qt = t >> 7, coff = qt * 4;
    float2 C0a, C0b, C1a, C1b, C2a, C2b, C3a, C3b;
    C0a=C0b=C1a=C1b=C2a=C2b=C3a=C3b = make_float2(0.f, 0.f);
    const float* h0 = reinterpret_cast<const float*>(regn)        + coff;
    const float* h1 = reinterpret_cast<const float*>(regn + 10240) + coff;
    const float* h2 = reinterpret_cast<const float*>(regn + 20480) + coff;
    const float* h3 = reinterpret_cast<const float*>(regn + 30720) + coff;
    for (int s = 22; s >= 0; --s) {
        const int m = q - s;
        if (m < 0) continue;
        float tp[7];
#pragma unroll
        for (int z = 0; z < 7; ++z) {
            const int tau = 4 * s - 3 + z;
            tp[z] = ((unsigned)tau < 88u) ? KERC.v[tau] : 0.0f;
        }
        const float4 r0 = *reinterpret_cast<const float4*>(h0 + (size_t)m * kHP1);
        const float4 r1 = *reinterpret_cast<const float4*>(h1 + (size_t)m * kHP1);
        const float4 r2 = *reinterpret_cast<const float4*>(h2 + (size_t)m * kHP1);
        const float4 r3 = *reinterpret_cast<const float4*>(h3 + (size_t)m * kHP1);
        // col d, row j: tap index z = d - j + 3
        ACCROW(C0a, C0b, r0, tp[3]) ACCROW(C0a, C0b, r1, tp[2])
        ACCROW(C0a, C0b, r2, tp[1]) ACCROW(C0a, C0b, r3, tp[0])
        ACCROW(C1a, C1b, r0, tp[4]) ACCROW(C1a, C1b, r1, tp[3])
        ACCROW(C1a, C1b, r2, tp[2]) ACCROW(C1a, C1b, r3, tp[1])
        ACCROW(C2a, C2b, r0, tp[5]) ACCROW(C2a, C2b, r1, tp[4])
        ACCROW(C2a, C2b, r2, tp[3]) ACCROW(C2a, C2b, r3, tp[2])
        ACCROW(C3a, C3b, r0, tp[6]) ACCROW(C3a, C3b, r1, tp[5])
        ACCROW(C3a, C3b, r2, tp[4]) ACCROW(C3a, C3b, r3, tp[3])
    }
    __syncthreads();   // all h reads complete (cur overwrites h region)

    // ---- cur store: 4 ch rows x int4 (cols 4q..4q+3), *64 exact, trunc ----
    {
        int* c0 = cur + (coff + 0) * kCURP1 + 4 * q;
        int* c1 = cur + (coff + 1) * kCURP1 + 4 * q;
        int* c2 = cur + (coff + 2) * kCURP1 + 4 * q;
        int* c3 = cur + (coff + 3) * kCURP1 + 4 * q;
        *reinterpret_cast<int4*>(c0) = make_int4(
            (int)(C0a.x * 64.0f), (int)(C1a.x * 64.0f),
            (int)(C2a.x * 64.0f), (int)(C3a.x * 64.0f));
        *reinterpret_cast<int4*>(c1) = make_int4(
            (int)(C0a.y * 64.0f), (int)(C1a.y * 64.0f),
            (int)(C2a.y * 64.0f), (int)(C3a.y * 64.0f));
        *reinterpret_cast<int4*>(c2) = make_int4(
            (int)(C0b.x * 64.0f), (int)(C1b.x * 64.0f),
            (int)(C2b.x * 64.0f), (int)(C3b.x * 64.0f));
        *reinterpret_cast<int4*>(c3) = make_int4(
            (int)(C0b.y * 64.0f), (int)(C1b.y * 64.0f),
            (int)(C2b.y * 64.0f), (int)(C3b.y * 64.0f));
    }
    __syncthreads();

    // ---- serial int32 Loihi dynamics (lanes 0..15), int2 reads ----
    if (t < kOT1) {
        const int2* cr2 = reinterpret_cast<const int2*>(cur + t * kCURP1);
        int u = 0, v = 0;
        sbuf[t * kSBP + 0] = 0;                   // delay_shift
        for (int s2 = 0; s2 < 256; ++s2) {
            const int2 c2 = cr2[s2];
            {
                const int un = (int)((unsigned)decay_i(u, 3072) + (unsigned)c2.x);
                int vn = (int)((unsigned)decay_i(v, 3968) + (unsigned)un);
                const int sp_ = (vn >= kTHETA) ? 1 : 0;
                if (sp_) vn = 0;
                u = un; v = vn;
                sbuf[t * kSBP + 2 * s2 + 1] = (unsigned char)sp_;
            }
            {
                const int un = (int)((unsigned)decay_i(u, 3072) + (unsigned)c2.y);
                int vn = (int)((unsigned)decay_i(v, 3968) + (unsigned)un);
                const int sp_ = (vn >= kTHETA) ? 1 : 0;
                if (sp_) vn = 0;
                u = un; v = vn;
                if (2 * s2 + 2 < kT) sbuf[t * kSBP + 2 * s2 + 2] = (unsigned char)sp_;
            }
        }
    }
    __syncthreads();

    // ---- pack 16 ch -> one ushort half of word-col (oblk>>1) ----
    {
        unsigned lo = 0, hi = 0;
#pragma unroll
        for (int j = 0; j < 8; ++j) {
            lo |= (unsigned)sbuf[j * kSBP + t] << j;
            hi |= (unsigned)sbuf[(8 + j) * kSBP + t] << j;
        }
        SPW[((((size_t)b * 32 + (oblk >> 1)) * kT) + t) * 2 + (oblk & 1)] =
            (unsigned short)(lo | (hi << 8));
    }
}

// ===== k2: word-walk GEMM over spike words + 2-col conv + scan (r13 form) ====
#define GW8(MW, BASE) { unsigned m_ = (MW); while (m_) { \
    const int bi_ = __ffs(m_) - 1; m_ &= m_ - 1; const int ii_ = (BASE) + bi_; \
    const float4 lo = *reinterpret_cast<const float4*>(&wlo[ii_ * 4]); \
    const float4 hi = *reinterpret_cast<const float4*>(&whi[ii_ * 4]); \
    A0 = pkadd(A0, make_float2(lo.x, lo.y)); A1 = pkadd(A1, make_float2(lo.z, lo.w)); \
    A2 = pkadd(A2, make_float2(hi.x, hi.y)); A3 = pkadd(A3, make_float2(hi.z, hi.w)); } }

#define ACC8(E0,E1,E2,E3, Q0,Q1, KV) \
    E0 = pkadd(E0, pkmul(make_float2(Q0.x, Q0.y), (KV))); \
    E1 = pkadd(E1, pkmul(make_float2(Q0.z, Q0.w), (KV))); \
    E2 = pkadd(E2, pkmul(make_float2(Q1.x, Q1.y), (KV))); \
    E3 = pkadd(E3, pkmul(make_float2(Q1.z, Q1.w), (KV)));

__global__ __launch_bounds__(512, 8) void k2_fused(const unsigned* __restrict__ SPW,
                                                   const float* __restrict__ W,
                                                   float* __restrict__ O) {
    // aliased region: W (32K) -> heven/hodd (2 x 12288) -> cur [8][522]
    __shared__ __align__(16) unsigned char regn[32768];
    __shared__ unsigned char sbuf[kOT2 * kSBP];   // 4128 B

    float* wlo   = reinterpret_cast<float*>(regn);           // [1024][4] ch0-3
    float* whi   = reinterpret_cast<float*>(regn + 16384);   // ch4-7
    float* heven = reinterpret_cast<float*>(regn);           // [256][12]
    float* hodd  = reinterpret_cast<float*>(regn + 12288);   // [256][12]
    int*   cur   = reinterpret_cast<int*>(regn);             // [8][522]

    const int t     = threadIdx.x;
    const int b     = blockIdx.x >> 5;            // 32 blocks per batch
    const int obase = (blockIdx.x & 31) * kOT2;

    for (int idx = t; idx < kOT2 * kHID; idx += 512) {
        const int j = idx >> 10, i = idx & 1023;
        const float w = W[(size_t)(obase + j) * kHID + i];
        if (j < 4) wlo[i * 4 + j] = w; else whi[i * 4 + (j - 4)] = w;
    }
    __syncthreads();

    // ---- coalesced word-mask reads + ordered gather (ascending i) ----
    const unsigned* sp = SPW + ((size_t)b * 32) * kT + t;
    float2 A0 = make_float2(0.f, 0.f), A1 = A0, A2 = A0, A3 = A0;
#pragma unroll 4
    for (int g = 0; g < 32; ++g) {
        const unsigned m = sp[(size_t)g * kT];
        GW8(m, g * 32)
    }
    __syncthreads();   // all W reads complete

    {
        float* hr = ((t & 1) ? hodd : heven) + (size_t)(t >> 1) * kHP2;
        *reinterpret_cast<float4*>(hr + 0) = make_float4(A0.x, A0.y, A1.x, A1.y);
        *reinterpret_cast<float4*>(hr + 4) = make_float4(A2.x, A2.y, A3.x, A3.y);
    }
    __syncthreads();

    float2 E0, E1, E2, E3, O0, O1, O2, O3;
    E0=E1=E2=E3=O0=O1=O2=O3 = make_float2(0.f, 0.f);
    const int q = t;
    if (t < 256) {
        for (int j = 0; j < 43; ++j) {
            const int m = q - 43 + j;
            const float t87 = KERC.v[87 - 2 * j];
            const float t86 = KERC.v[86 - 2 * j];
            const float t85 = KERC.v[85 - 2 * j];
            if (m >= 0) {
                const float* he = heven + (size_t)m * kHP2;
                const float* ho = hodd  + (size_t)m * kHP2;
                const float4 a0 = *reinterpret_cast<const float4*>(he + 0);
                const float4 a1 = *reinterpret_cast<const float4*>(he + 4);
                const float4 b0 = *reinterpret_cast<const float4*>(ho + 0);
                const float4 b1 = *reinterpret_cast<const float4*>(ho + 4);
                ACC8(E0,E1,E2,E3, a0,a1, t86)
                ACC8(E0,E1,E2,E3, b0,b1, t85)
                ACC8(O0,O1,O2,O3, a0,a1, t87)
                ACC8(O0,O1,O2,O3, b0,b1, t86)
            }
        }
        {
            const float* he = heven + (size_t)q * kHP2;
            const float* ho = hodd  + (size_t)q * kHP2;
            const float4 a0 = *reinterpret_cast<const float4*>(he + 0);
            const float4 a1 = *reinterpret_cast<const float4*>(he + 4);
            const float4 b0 = *reinterpret_cast<const float4*>(ho + 0);
            const float4 b1 = *reinterpret_cast<const float4*>(ho + 4);
            const float v1 = KERC.v[1];
            ACC8(E0,E1,E2,E3, a0,a1, 1.0f)
            ACC8(O0,O1,O2,O3, a0,a1, v1)
            ACC8(O0,O1,O2,O3, b0,b1, 1.0f)
        }
    }
    __syncthreads();

    if (t < 256) {
#define CST2(CH, EV, OV) \
        *reinterpret_cast<int2*>(cur + (CH) * kCURP2 + 2 * q) = \
            make_int2((int)((EV) * 64.0f), (int)((OV) * 64.0f));
        CST2(0, E0.x, O0.x) CST2(1, E0.y, O0.y)
        CST2(2, E1.x, O1.x) CST2(3, E1.y, O1.y)
        CST2(4, E2.x, O2.x) CST2(5, E2.y, O2.y)
        CST2(6, E3.x, O3.x) CST2(7, E3.y, O3.y)
#undef CST2
    }
    __syncthreads();

    if (t < kOT2) {
        const int2* cr2 = reinterpret_cast<const int2*>(cur + t * kCURP2);
        int u = 0, v = 0;
        sbuf[t * kSBP + 0] = 0;                   // delay_shift on output
        for (int s2 = 0; s2 < 256; ++s2) {
            const int2 c2 = cr2[s2];
            {
                const int un = (int)((unsigned)decay_i(u, 3072) + (unsigned)c2.x);
                int vn = (int)((unsigned)decay_i(v, 3968) + (unsigned)un);
                const int sp2 = (vn >= kTHETA) ? 1 : 0;
                if (sp2) vn = 0;
                u = un; v = vn;
                sbuf[t * kSBP + 2 * s2 + 1] = (unsigned char)sp2;
            }
            {
                const int un = (int)((unsigned)decay_i(u, 3072) + (unsigned)c2.y);
                int vn = (int)((unsigned)decay_i(v, 3968) + (unsigned)un);
                const int sp2 = (vn >= kTHETA) ? 1 : 0;
                if (sp2) vn = 0;
                u = un; v = vn;
                if (2 * s2 + 2 < kT) sbuf[t * kSBP + 2 * s2 + 2] = (unsigned char)sp2;
            }
        }
    }
    __syncthreads();

    for (int idx = t; idx < kOT2 * kT; idx += 512) {
        const int j = idx >> 9, tt = idx & 511;
        O[((size_t)(b * kCOUT + obase + j)) * kT + tt] = (float)sbuf[j * kSBP + tt];
    }
}

__global__ void k_mark(float* __restrict__ out0, float v) {
    if (threadIdx.x == 0 && blockIdx.x == 0) out0[0] = v;
}

extern "C" void kernel_launch(void* const* d_in, const int* in_sizes, int n_in,
                              void* d_out, int out_size, void* d_ws, size_t ws_size,
                              hipStream_t stream) {
    const float* X  = (const float*)d_in[0];   // (32,512,1,1,512) spikes {0,1}
    const float* W1 = (const float*)d_in[1];   // (1024,512)
    const float* W2 = (const float*)d_in[2];   // (256,1024)
    float* OUT = (float*)d_out;                // (32,256,1,1,512)

    const size_t xl_bytes  = (size_t)kB * kT * kLCAP * 2;     // 4 MiB
    const size_t xc_bytes  = (size_t)kB * kT * 2;             // 32 KiB
    const size_t spw_bytes = (size_t)kB * 32 * kT * 4;        // 2 MiB
    const size_t need = xl_bytes + xc_bytes + spw_bytes;

    if (n_in != 3 || in_sizes[0] != kB * kCIN * kT || in_sizes[1] != kHID * kCIN ||
        in_sizes[2] != kCOUT * kHID || out_size != kB * kCOUT * kT) {
        hipLaunchKernelGGL(k_mark, dim3(1), dim3(64), 0, stream, OUT, 7000001.0f);
        return;
    }
    if (ws_size < need || d_ws == nullptr) {
        const float v = (float)(8000000u + (unsigned)((ws_size >> 10) % 900000));
        hipLaunchKernelGGL(k_mark, dim3(1), dim3(64), 0, stream, OUT, v);
        return;
    }

    char* ws = (char*)d_ws;
    unsigned short* xl  = (unsigned short*)ws;
    unsigned short* xc  = (unsigned short*)(ws + xl_bytes);
    unsigned short* spw = (unsigned short*)(ws + xl_bytes + xc_bytes);

    hipLaunchKernelGGL(k0_list, dim3(kB * kT / 256), dim3(256), 0, stream,
                       X, xl, xc);
    hipLaunchKernelGGL(k1_fused, dim3(kB * (kHID / kOT1)), dim3(512), 0, stream,
                       xl, xc, W1, spw);
    hipLaunchKernelGGL(k2_fused, dim3(kB * (kCOUT / kOT2)), dim3(512), 0, stream,
                       (const unsigned*)spw, W2, OUT);
}

// Round 19
// 380.991 us; speedup vs baseline: 1.3512x; 1.3512x over previous
//
#include <hip/hip_runtime.h>

// SlayerLoihiMLP: bit-exact f32 replication of the numpy reference (verified
// r5-r18, absmax 0.0). Round 19 = exact restore of r15/r17 (best known,
// 381 us, reproduced twice). r18's fused prelude collapsed occupancy to 2.9%
// (64 blocks) and cost +134 us — two-kernel prelude is the proven optimum.
// k1: list-gather + 4col/4ch conv + fused scan (224 us, latency-plateau).
// k2: sparse word-walk gather + 2-col conv + fused scan (135 us, at its
// ordered-sum instruction floor).
// Exactness invariants:
//  - GEMM: per-output ordered ascending-i f32 sum; skipping x==0 terms is
//    bit-exact (RNE running sums never produce -0.0; +0.0 adds are identity).
//  - conv: f32 mul then add (contract OFF file-wide), taps tau-descending
//    87..0 per output col; out-of-range taps fetched as exact 0.0f (their
//    mul/add terms are IEEE identities); taps = (64*SRM)/64 exact; *64; trunc.
//  - neuron dynamics: bit-exact int32 with jnp wrap semantics (decay_i).
//  - float2 packing pairs INDEPENDENT channel accumulators.

#pragma clang fp contract(off)

constexpr int kT     = 512;
constexpr int kCIN   = 512;
constexpr int kHID   = 1024;
constexpr int kCOUT  = 256;
constexpr int kB     = 32;
constexpr int kTHETA = 5120;   // 80 << 6
constexpr int kOT1   = 16;     // k1 channels per block
constexpr int kOT2   = 8;      // k2 channels per block
constexpr int kHP1   = 20;     // k1 h row pitch (floats): 80B, 8-lane period
                               // covers all 32 banks -> conflict-free b128
constexpr int kHP2   = 12;     // k2 h row pitch (r13-proven)
constexpr int kSBP   = 516;    // sbuf row pitch (bytes)
constexpr int kCURP1 = 524;    // k1 cur pitch (ints): int4-aligned stores
constexpr int kCURP2 = 522;    // k2 cur pitch (r13-proven)
constexpr int kLCAP  = 128;    // list capacity per (b,t); mean nnz=25.6

// ---- SRM kernel taps at compile time: v[tau] = (64*SRM_KERNEL[tau])/64 ----
struct Ker { float v[96]; int n; };
constexpr Ker mk_ker() {
    Ker K{}; int u = 64, v = 64; K.v[0] = 1.0f; int i = 1;
    while (v > 0 && i < 96) {
        u = (u * 3072) >> 12;
        v = ((v * 3968) >> 12) + u;
        K.v[i++] = (float)v / 64.0f;   // exact (v <= 194)
    }
    K.n = i; return K;
}
constexpr Ker KER = mk_ker();
static_assert(KER.n == 88, "SRM kernel length must be 88");
static_assert(KER.v[87] == 0.0f, "tap 87 must be the exact zero tail tap");
__device__ __constant__ Ker KERC = mk_ker();

__device__ __forceinline__ float2 pkmul(const float2 a, const float b) {
    return make_float2(a.x * b, a.y * b);
}
__device__ __forceinline__ float2 pkadd(const float2 a, const float2 b) {
    return make_float2(a.x + b.x, a.y + b.y);
}

// wrap-exact mirror of jnp: s = sign(x); s * ((s*x*mult) >> 12), int32 wrap
__device__ __forceinline__ int decay_i(int x, int mult) {
    unsigned ax = (x >= 0) ? (unsigned)x : (0u - (unsigned)x);
    unsigned p  = ax * (unsigned)mult;
    int sh = ((int)p) >> 12;
    return (x >= 0) ? sh : (int)(0u - (unsigned)sh);
}

// =============== k0: pack X into bit masks XPW[b][w=i/32][t] =================
__global__ __launch_bounds__(256) void k0_pack(const float* __restrict__ X,
                                               unsigned* __restrict__ XPW) {
    const int tid = blockIdx.x * 256 + threadIdx.x;   // [b][w][t] flat
    const int b = tid >> 13, rem = tid & 8191, w = rem >> 9, t = rem & 511;
    const float* xp = X + ((size_t)(b * kCIN + w * 32)) * kT + t;
    unsigned m = 0;
#pragma unroll
    for (int k = 0; k < 32; ++k)
        m |= (xp[(size_t)k * kT] != 0.0f ? 1u : 0u) << k;
    XPW[tid] = m;
}

// ======= k0b: masks -> per-(b,t) ascending index lists XL[bt][k], XC[bt] =====
__global__ __launch_bounds__(256) void k0b_list(const unsigned* __restrict__ XPW,
                                                unsigned short* __restrict__ XL,
                                                unsigned short* __restrict__ XC) {
    const int bt = blockIdx.x * 256 + threadIdx.x;    // b*512 + t
    const int b = bt >> 9, t = bt & 511;
    const unsigned* xw = XPW + ((size_t)b * 16) * kT + t;
    unsigned short* row = XL + (size_t)bt * kLCAP;
    int cnt = 0;
    for (int w = 0; w < 16; ++w) {
        unsigned m = xw[(size_t)w * kT];
        while (m) {
            const int bi = __ffs(m) - 1; m &= m - 1;
            if (cnt < kLCAP) row[cnt] = (unsigned short)(w * 32 + bi);
            ++cnt;
        }
    }
    XC[bt] = (unsigned short)min(cnt, kLCAP);
}

// ===== k1: list-gather GEMM + 4col/4ch conv + int32 scan; 16 ch/block ========
#define GADD16(II) { const int ii_ = (II); \
    const float4 f0 = *reinterpret_cast<const float4*>(&w0[ii_ * 4]); \
    const float4 f1 = *reinterpret_cast<const float4*>(&w1[ii_ * 4]); \
    const float4 f2 = *reinterpret_cast<const float4*>(&w2[ii_ * 4]); \
    const float4 f3 = *reinterpret_cast<const float4*>(&w3[ii_ * 4]); \
    A0 = pkadd(A0, make_float2(f0.x, f0.y)); A1 = pkadd(A1, make_float2(f0.z, f0.w)); \
    A2 = pkadd(A2, make_float2(f1.x, f1.y)); A3 = pkadd(A3, make_float2(f1.z, f1.w)); \
    A4 = pkadd(A4, make_float2(f2.x, f2.y)); A5 = pkadd(A5, make_float2(f2.z, f2.w)); \
    A6 = pkadd(A6, make_float2(f3.x, f3.y)); A7 = pkadd(A7, make_float2(f3.z, f3.w)); }

// accumulate one h row (4 ch as float4 R) into col-d accs with tap KV
#define ACCROW(CA, CB, R, KV) \
    CA = pkadd(CA, pkmul(make_float2((R).x, (R).y), (KV))); \
    CB = pkadd(CB, pkmul(make_float2((R).z, (R).w), (KV)));

__global__ __launch_bounds__(512, 6) void k1_fused(const unsigned short* __restrict__ XL,
                                                   const unsigned short* __restrict__ XC,
                                                   const float* __restrict__ W,
                                                   unsigned short* __restrict__ SPW) {
    // aliased region: W (32K) -> h row-mod-4 arrays 4 x [128][20] (40960B)
    //                 -> cur [16][524] (33536B)
    __shared__ __align__(16) unsigned char regn[40960];
    __shared__ unsigned char sbuf[kOT1 * kSBP];   // 8256 B

    float* w0 = reinterpret_cast<float*>(regn);            // [512][4] ch0-3
    float* w1 = reinterpret_cast<float*>(regn + 8192);     // ch4-7
    float* w2 = reinterpret_cast<float*>(regn + 16384);    // ch8-11
    float* w3 = reinterpret_cast<float*>(regn + 24576);    // ch12-15
    int*   cur = reinterpret_cast<int*>(regn);             // [16][524]

    const int t     = threadIdx.x;
    const int b     = blockIdx.x >> 6;            // 64 blocks per batch
    const int oblk  = blockIdx.x & 63;
    const int obase = oblk * kOT1;

    for (int idx = t; idx < kOT1 * kCIN; idx += 512) {
        const int j = idx >> 9, i = idx & 511;    // j = channel 0..15
        float* wq = reinterpret_cast<float*>(regn + (j >> 2) * 8192);
        wq[i * 4 + (j & 3)] = W[(size_t)(obase + j) * kCIN + i];
    }
    __syncthreads();

    // ---- list gather: ordered ascending-i adds of W columns where x==1 ----
    const int bt = (b << 9) | t;
    const int cnt = XC[bt];
    const uint4* lrow = reinterpret_cast<const uint4*>(XL + (size_t)bt * kLCAP);
    float2 A0 = make_float2(0.f, 0.f), A1 = A0, A2 = A0, A3 = A0,
           A4 = A0, A5 = A0, A6 = A0, A7 = A0;
    for (int k8 = 0; k8 * 8 < cnt; ++k8) {
        const uint4 le = lrow[k8];
        const int base = k8 * 8;
#define GE1(E, V) if (base + (E) < cnt) GADD16((int)(V))
        GE1(0, le.x & 0xffffu) GE1(1, le.x >> 16)
        GE1(2, le.y & 0xffffu) GE1(3, le.y >> 16)
        GE1(4, le.z & 0xffffu) GE1(5, le.z >> 16)
        GE1(6, le.w & 0xffffu) GE1(7, le.w >> 16)
#undef GE1
    }
    __syncthreads();   // all W reads complete (h overwrites W region)

    // ---- stage h row t into array (t&3), row (t>>2): 16 ch + 4 pad ----
    {
        float* hr = reinterpret_cast<float*>(regn + (t & 3) * 10240)
                    + (size_t)(t >> 2) * kHP1;
        *reinterpret_cast<float4*>(hr + 0)  = make_float4(A0.x, A0.y, A1.x, A1.y);
        *reinterpret_cast<float4*>(hr + 4)  = make_float4(A2.x, A2.y, A3.x, A3.y);
        *reinterpret_cast<float4*>(hr + 8)  = make_float4(A4.x, A4.y, A5.x, A5.y);
        *reinterpret_cast<float4*>(hr + 12) = make_float4(A6.x, A6.y, A7.x, A7.y);
    }
    __syncthreads();

    // ---- conv: thread (q = t&127, qt = t>>7) -> cols 4q..4q+3, ch 4qt..+3 ----
    // iterate s = q-m descending 22..0 (rows ascending); per col d the tap
    // sequence is tau = 4s+d-j, strictly descending 87..0 across the loop;
    // out-of-range taus fetch exact 0.0f (identity terms).
    const int q = t & 127, qt = t >> 7, coff = qt * 4;
    float2 C0a, C0b, C1a, C1b, C2a, C2b, C3a, C3b;
    C0a=C0b=C1a=C1b=C2a=C2b=C3a=C3b = make_float2(0.f, 0.f);
    const float* h0 = reinterpret_cast<const float*>(regn)        + coff;
    const float* h1 = reinterpret_cast<const float*>(regn + 10240) + coff;
    const float* h2 = reinterpret_cast<const float*>(regn + 20480) + coff;
    const float* h3 = reinterpret_cast<const float*>(regn + 30720) + coff;
    for (int s = 22; s >= 0; --s) {
        const int m = q - s;
        if (m < 0) continue;
        float tp[7];
#pragma unroll
        for (int z = 0; z < 7; ++z) {
            const int tau = 4 * s - 3 + z;
            tp[z] = ((unsigned)tau < 88u) ? KERC.v[tau] : 0.0f;
        }
        const float4 r0 = *reinterpret_cast<const float4*>(h0 + (size_t)m * kHP1);
        const float4 r1 = *reinterpret_cast<const float4*>(h1 + (size_t)m * kHP1);
        const float4 r2 = *reinterpret_cast<const float4*>(h2 + (size_t)m * kHP1);
        const float4 r3 = *reinterpret_cast<const float4*>(h3 + (size_t)m * kHP1);
        // col d, row j: tap index z = d - j + 3
        ACCROW(C0a, C0b, r0, tp[3]) ACCROW(C0a, C0b, r1, tp[2])
        ACCROW(C0a, C0b, r2, tp[1]) ACCROW(C0a, C0b, r3, tp[0])
        ACCROW(C1a, C1b, r0, tp[4]) ACCROW(C1a, C1b, r1, tp[3])
        ACCROW(C1a, C1b, r2, tp[2]) ACCROW(C1a, C1b, r3, tp[1])
        ACCROW(C2a, C2b, r0, tp[5]) ACCROW(C2a, C2b, r1, tp[4])
        ACCROW(C2a, C2b, r2, tp[3]) ACCROW(C2a, C2b, r3, tp[2])
        ACCROW(C3a, C3b, r0, tp[6]) ACCROW(C3a, C3b, r1, tp[5])
        ACCROW(C3a, C3b, r2, tp[4]) ACCROW(C3a, C3b, r3, tp[3])
    }
    __syncthreads();   // all h reads complete (cur overwrites h region)

    // ---- cur store: 4 ch rows x int4 (cols 4q..4q+3), *64 exact, trunc ----
    {
        int* c0 = cur + (coff + 0) * kCURP1 + 4 * q;
        int* c1 = cur + (coff + 1) * kCURP1 + 4 * q;
        int* c2 = cur + (coff + 2) * kCURP1 + 4 * q;
        int* c3 = cur + (coff + 3) * kCURP1 + 4 * q;
        *reinterpret_cast<int4*>(c0) = make_int4(
            (int)(C0a.x * 64.0f), (int)(C1a.x * 64.0f),
            (int)(C2a.x * 64.0f), (int)(C3a.x * 64.0f));
        *reinterpret_cast<int4*>(c1) = make_int4(
            (int)(C0a.y * 64.0f), (int)(C1a.y * 64.0f),
            (int)(C2a.y * 64.0f), (int)(C3a.y * 64.0f));
        *reinterpret_cast<int4*>(c2) = make_int4(
            (int)(C0b.x * 64.0f), (int)(C1b.x * 64.0f),
            (int)(C2b.x * 64.0f), (int)(C3b.x * 64.0f));
        *reinterpret_cast<int4*>(c3) = make_int4(
            (int)(C0b.y * 64.0f), (int)(C1b.y * 64.0f),
            (int)(C2b.y * 64.0f), (int)(C3b.y * 64.0f));
    }
    __syncthreads();

    // ---- serial int32 Loihi dynamics (lanes 0..15), int2 reads ----
    if (t < kOT1) {
        const int2* cr2 = reinterpret_cast<const int2*>(cur + t * kCURP1);
        int u = 0, v = 0;
        sbuf[t * kSBP + 0] = 0;                   // delay_shift
        for (int s2 = 0; s2 < 256; ++s2) {
            const int2 c2 = cr2[s2];
            {
                const int un = (int)((unsigned)decay_i(u, 3072) + (unsigned)c2.x);
                int vn = (int)((unsigned)decay_i(v, 3968) + (unsigned)un);
                const int sp_ = (vn >= kTHETA) ? 1 : 0;
                if (sp_) vn = 0;
                u = un; v = vn;
                sbuf[t * kSBP + 2 * s2 + 1] = (unsigned char)sp_;
            }
            {
                const int un = (int)((unsigned)decay_i(u, 3072) + (unsigned)c2.y);
                int vn = (int)((unsigned)decay_i(v, 3968) + (unsigned)un);
                const int sp_ = (vn >= kTHETA) ? 1 : 0;
                if (sp_) vn = 0;
                u = un; v = vn;
                if (2 * s2 + 2 < kT) sbuf[t * kSBP + 2 * s2 + 2] = (unsigned char)sp_;
            }
        }
    }
    __syncthreads();

    // ---- pack 16 ch -> one ushort half of word-col (oblk>>1) ----
    {
        unsigned lo = 0, hi = 0;
#pragma unroll
        for (int j = 0; j < 8; ++j) {
            lo |= (unsigned)sbuf[j * kSBP + t] << j;
            hi |= (unsigned)sbuf[(8 + j) * kSBP + t] << j;
        }
        SPW[((((size_t)b * 32 + (oblk >> 1)) * kT) + t) * 2 + (oblk & 1)] =
            (unsigned short)(lo | (hi << 8));
    }
}

// ===== k2: word-walk GEMM over spike words + 2-col conv + scan (r13 form) ====
#define GW8(MW, BASE) { unsigned m_ = (MW); while (m_) { \
    const int bi_ = __ffs(m_) - 1; m_ &= m_ - 1; const int ii_ = (BASE) + bi_; \
    const float4 lo = *reinterpret_cast<const float4*>(&wlo[ii_ * 4]); \
    const float4 hi = *reinterpret_cast<const float4*>(&whi[ii_ * 4]); \
    A0 = pkadd(A0, make_float2(lo.x, lo.y)); A1 = pkadd(A1, make_float2(lo.z, lo.w)); \
    A2 = pkadd(A2, make_float2(hi.x, hi.y)); A3 = pkadd(A3, make_float2(hi.z, hi.w)); } }

#define ACC8(E0,E1,E2,E3, Q0,Q1, KV) \
    E0 = pkadd(E0, pkmul(make_float2(Q0.x, Q0.y), (KV))); \
    E1 = pkadd(E1, pkmul(make_float2(Q0.z, Q0.w), (KV))); \
    E2 = pkadd(E2, pkmul(make_float2(Q1.x, Q1.y), (KV))); \
    E3 = pkadd(E3, pkmul(make_float2(Q1.z, Q1.w), (KV)));

__global__ __launch_bounds__(512, 8) void k2_fused(const unsigned* __restrict__ SPW,
                                                   const float* __restrict__ W,
                                                   float* __restrict__ O) {
    // aliased region: W (32K) -> heven/hodd (2 x 12288) -> cur [8][522]
    __shared__ __align__(16) unsigned char regn[32768];
    __shared__ unsigned char sbuf[kOT2 * kSBP];   // 4128 B

    float* wlo   = reinterpret_cast<float*>(regn);           // [1024][4] ch0-3
    float* whi   = reinterpret_cast<float*>(regn + 16384);   // ch4-7
    float* heven = reinterpret_cast<float*>(regn);           // [256][12]
    float* hodd  = reinterpret_cast<float*>(regn + 12288);   // [256][12]
    int*   cur   = reinterpret_cast<int*>(regn);             // [8][522]

    const int t     = threadIdx.x;
    const int b     = blockIdx.x >> 5;            // 32 blocks per batch
    const int obase = (blockIdx.x & 31) * kOT2;

    for (int idx = t; idx < kOT2 * kHID; idx += 512) {
        const int j = idx >> 10, i = idx & 1023;
        const float w = W[(size_t)(obase + j) * kHID + i];
        if (j < 4) wlo[i * 4 + j] = w; else whi[i * 4 + (j - 4)] = w;
    }
    __syncthreads();

    // ---- coalesced word-mask reads + ordered gather (ascending i) ----
    const unsigned* sp = SPW + ((size_t)b * 32) * kT + t;
    float2 A0 = make_float2(0.f, 0.f), A1 = A0, A2 = A0, A3 = A0;
#pragma unroll 4
    for (int g = 0; g < 32; ++g) {
        const unsigned m = sp[(size_t)g * kT];
        GW8(m, g * 32)
    }
    __syncthreads();   // all W reads complete

    {
        float* hr = ((t & 1) ? hodd : heven) + (size_t)(t >> 1) * kHP2;
        *reinterpret_cast<float4*>(hr + 0) = make_float4(A0.x, A0.y, A1.x, A1.y);
        *reinterpret_cast<float4*>(hr + 4) = make_float4(A2.x, A2.y, A3.x, A3.y);
    }
    __syncthreads();

    float2 E0, E1, E2, E3, O0, O1, O2, O3;
    E0=E1=E2=E3=O0=O1=O2=O3 = make_float2(0.f, 0.f);
    const int q = t;
    if (t < 256) {
        for (int j = 0; j < 43; ++j) {
            const int m = q - 43 + j;
            const float t87 = KERC.v[87 - 2 * j];
            const float t86 = KERC.v[86 - 2 * j];
            const float t85 = KERC.v[85 - 2 * j];
            if (m >= 0) {
                const float* he = heven + (size_t)m * kHP2;
                const float* ho = hodd  + (size_t)m * kHP2;
                const float4 a0 = *reinterpret_cast<const float4*>(he + 0);
                const float4 a1 = *reinterpret_cast<const float4*>(he + 4);
                const float4 b0 = *reinterpret_cast<const float4*>(ho + 0);
                const float4 b1 = *reinterpret_cast<const float4*>(ho + 4);
                ACC8(E0,E1,E2,E3, a0,a1, t86)
                ACC8(E0,E1,E2,E3, b0,b1, t85)
                ACC8(O0,O1,O2,O3, a0,a1, t87)
                ACC8(O0,O1,O2,O3, b0,b1, t86)
            }
        }
        {
            const float* he = heven + (size_t)q * kHP2;
            const float* ho = hodd  + (size_t)q * kHP2;
            const float4 a0 = *reinterpret_cast<const float4*>(he + 0);
            const float4 a1 = *reinterpret_cast<const float4*>(he + 4);
            const float4 b0 = *reinterpret_cast<const float4*>(ho + 0);
            const float4 b1 = *reinterpret_cast<const float4*>(ho + 4);
            const float v1 = KERC.v[1];
            ACC8(E0,E1,E2,E3, a0,a1, 1.0f)
            ACC8(O0,O1,O2,O3, a0,a1, v1)
            ACC8(O0,O1,O2,O3, b0,b1, 1.0f)
        }
    }
    __syncthreads();

    if (t < 256) {
#define CST2(CH, EV, OV) \
        *reinterpret_cast<int2*>(cur + (CH) * kCURP2 + 2 * q) = \
            make_int2((int)((EV) * 64.0f), (int)((OV) * 64.0f));
        CST2(0, E0.x, O0.x) CST2(1, E0.y, O0.y)
        CST2(2, E1.x, O1.x) CST2(3, E1.y, O1.y)
        CST2(4, E2.x, O2.x) CST2(5, E2.y, O2.y)
        CST2(6, E3.x, O3.x) CST2(7, E3.y, O3.y)
#undef CST2
    }
    __syncthreads();

    if (t < kOT2) {
        const int2* cr2 = reinterpret_cast<const int2*>(cur + t * kCURP2);
        int u = 0, v = 0;
        sbuf[t * kSBP + 0] = 0;                   // delay_shift on output
        for (int s2 = 0; s2 < 256; ++s2) {
            const int2 c2 = cr2[s2];
            {
                const int un = (int)((unsigned)decay_i(u, 3072) + (unsigned)c2.x);
                int vn = (int)((unsigned)decay_i(v, 3968) + (unsigned)un);
                const int sp2 = (vn >= kTHETA) ? 1 : 0;
                if (sp2) vn = 0;
                u = un; v = vn;
                sbuf[t * kSBP + 2 * s2 + 1] = (unsigned char)sp2;
            }
            {
                const int un = (int)((unsigned)decay_i(u, 3072) + (unsigned)c2.y);
                int vn = (int)((unsigned)decay_i(v, 3968) + (unsigned)un);
                const int sp2 = (vn >= kTHETA) ? 1 : 0;
                if (sp2) vn = 0;
                u = un; v = vn;
                if (2 * s2 + 2 < kT) sbuf[t * kSBP + 2 * s2 + 2] = (unsigned char)sp2;
            }
        }
    }
    __syncthreads();

    for (int idx = t; idx < kOT2 * kT; idx += 512) {
        const int j = idx >> 9, tt = idx & 511;
        O[((size_t)(b * kCOUT + obase + j)) * kT + tt] = (float)sbuf[j * kSBP + tt];
    }
}

__global__ void k_mark(float* __restrict__ out0, float v) {
    if (threadIdx.x == 0 && blockIdx.x == 0) out0[0] = v;
}

extern "C" void kernel_launch(void* const* d_in, const int* in_sizes, int n_in,
                              void* d_out, int out_size, void* d_ws, size_t ws_size,
                              hipStream_t stream) {
    const float* X  = (const float*)d_in[0];   // (32,512,1,1,512) spikes {0,1}
    const float* W1 = (const float*)d_in[1];   // (1024,512)
    const float* W2 = (const float*)d_in[2];   // (256,1024)
    float* OUT = (float*)d_out;                // (32,256,1,1,512)

    const size_t xpw_bytes = (size_t)kB * 16 * kT * 4;        // 1 MiB
    const size_t spw_bytes = (size_t)kB * 32 * kT * 4;        // 2 MiB
    const size_t xl_bytes  = (size_t)kB * kT * kLCAP * 2;     // 4 MiB
    const size_t xc_bytes  = (size_t)kB * kT * 2;             // 32 KiB
    const size_t need = xpw_bytes + spw_bytes + xl_bytes + xc_bytes;

    if (n_in != 3 || in_sizes[0] != kB * kCIN * kT || in_sizes[1] != kHID * kCIN ||
        in_sizes[2] != kCOUT * kHID || out_size != kB * kCOUT * kT) {
        hipLaunchKernelGGL(k_mark, dim3(1), dim3(64), 0, stream, OUT, 7000001.0f);
        return;
    }
    if (ws_size < need || d_ws == nullptr) {
        const float v = (float)(8000000u + (unsigned)((ws_size >> 10) % 900000));
        hipLaunchKernelGGL(k_mark, dim3(1), dim3(64), 0, stream, OUT, v);
        return;
    }

    char* ws = (char*)d_ws;
    unsigned*       xpw = (unsigned*)ws;
    unsigned short* spw = (unsigned short*)(ws + xpw_bytes);
    unsigned short* xl  = (unsigned short*)(ws + xpw_bytes + spw_bytes);
    unsigned short* xc  = (unsigned short*)(ws + xpw_bytes + spw_bytes + xl_bytes);

    hipLaunchKernelGGL(k0_pack, dim3(kB * 16 * kT / 256), dim3(256), 0, stream,
                       X, xpw);
    hipLaunchKernelGGL(k0b_list, dim3(kB * kT / 256), dim3(256), 0, stream,
                       xpw, xl, xc);
    hipLaunchKernelGGL(k1_fused, dim3(kB * (kHID / kOT1)), dim3(512), 0, stream,
                       xl, xc, W1, spw);
    hipLaunchKernelGGL(k2_fused, dim3(kB * (kCOUT / kOT2)), dim3(512), 0, stream,
                       (const unsigned*)spw, W2, OUT);
}